// Round 9
// baseline (585.969 us; speedup 1.0000x reference)
//
#include <hip/hip_runtime.h>
#include <cmath>

typedef unsigned short u16;
typedef unsigned int u32;
typedef short bf16x8 __attribute__((ext_vector_type(8)));
typedef float f32x4 __attribute__((ext_vector_type(4)));

#define NN 50000      // nodes
#define MP 50048      // padded to 64
#define EE 400000     // raw edges
#define ET 450000     // edges + self loops
#define HIDD 256
#define KIN 192       // 3*F
#define LN_EPSF 1e-5f

__device__ __forceinline__ float bf2f(u16 u){ return __uint_as_float(((u32)u)<<16); }
__device__ __forceinline__ u16 f2bf(float f){
  u32 x = __float_as_uint(f);
  u32 r = x + 0x7fffu + ((x>>16)&1u);   // RNE
  return (u16)(r>>16);
}
__device__ __forceinline__ float bflo(u32 v){ return __uint_as_float(v<<16); }
__device__ __forceinline__ float bfhi(u32 v){ return __uint_as_float(v & 0xffff0000u); }
__device__ __forceinline__ u32 pack2(float a, float b){ return (u32)f2bf(a) | ((u32)f2bf(b)<<16); }

__device__ __forceinline__ void dma16(const u16* g, u16* lds){
  __builtin_amdgcn_global_load_lds(
      (const __attribute__((address_space(1))) void*)g,
      (__attribute__((address_space(3))) void*)lds, 16, 0, 0);
}

// ---------------- CSR build ----------------
__global__ void k_degree(const int* __restrict__ ei, int* __restrict__ deg){
  int i = blockIdx.x*blockDim.x + threadIdx.x;
  if (i >= ET) return;
  int d = (i < EE) ? ei[EE + i] : (i - EE);
  atomicAdd(&deg[d], 1);
}

__global__ void k_scan1(const int* __restrict__ deg, int* __restrict__ row_off, int* __restrict__ part){
  __shared__ int s[256];
  int n = blockIdx.x*256 + threadIdx.x;
  int v = (n < NN) ? deg[n] : 0;
  s[threadIdx.x] = v;
  __syncthreads();
  for (int off=1; off<256; off<<=1){
    int t = (threadIdx.x >= off) ? s[threadIdx.x - off] : 0;
    __syncthreads();
    s[threadIdx.x] += t;
    __syncthreads();
  }
  if (n < NN) row_off[n] = s[threadIdx.x] - v;
  if (threadIdx.x == 255) part[blockIdx.x] = s[255];
}

__global__ void k_scan2(int* __restrict__ part, int nparts){
  __shared__ int s[256];
  int v = (threadIdx.x < nparts) ? part[threadIdx.x] : 0;
  s[threadIdx.x] = v;
  __syncthreads();
  for (int off=1; off<256; off<<=1){
    int t = (threadIdx.x >= off) ? s[threadIdx.x - off] : 0;
    __syncthreads();
    s[threadIdx.x] += t;
    __syncthreads();
  }
  if (threadIdx.x < nparts) part[threadIdx.x] = s[threadIdx.x] - v;
}

__global__ void k_scan3(int* __restrict__ row_off, const int* __restrict__ part){
  int n = blockIdx.x*256 + threadIdx.x;
  if (n < NN) row_off[n] += part[blockIdx.x];
}

__global__ void k_scatter(const int* __restrict__ ei, const int* __restrict__ row_off,
                          int* __restrict__ cur, int* __restrict__ csr_src){
  int i = blockIdx.x*blockDim.x + threadIdx.x;
  if (i >= ET) return;
  int s, d;
  if (i < EE){ s = ei[i]; d = ei[EE + i]; } else { s = i - EE; d = i - EE; }
  int pos = row_off[d] + atomicAdd(&cur[d], 1);
  csr_src[pos] = s;
}

// ---------------- feats = [x | remb[rid] | posenc] as bf16 [MP][192], pad rows zeroed ----------------
__global__ __launch_bounds__(256) void k_feats(
    const float* __restrict__ x, const float* __restrict__ remb,
    const int* __restrict__ rid, u16* __restrict__ feats)
{
  int e = blockIdx.x*768 + threadIdx.x;
  #pragma unroll
  for (int it=0; it<3; ++it, e+=256){
    int n = e / 192;
    int c = e - n*192;
    if (n >= MP) break;
    float v = 0.f;
    if (n < NN){
      if (c < 64){
        v = x[n*64 + c];
      } else if (c < 128){
        v = remb[rid[n]*64 + (c-64)];
      } else {
        int i = c - 128;
        float rate = exp2f(-(float)(2*(i>>1)) * (1.0f/64.0f) * 13.287712379549449f);
        float s, cc;
        sincosf((float)n * rate, &s, &cc);
        v = (i & 1) ? cc : s;
      }
    }
    feats[(size_t)n*192 + c] = f2bf(v);
  }
}

// ---------------- weight convert+transpose to bf16 Wt[N][K] ----------------
__global__ __launch_bounds__(256) void k_wt(
    const float* __restrict__ ipw, const float* __restrict__ gatw,
    u16* __restrict__ wtin, u16* __restrict__ wtl)
{
  int idx = blockIdx.x*256 + threadIdx.x;
  if (idx < 49152){               // inproj: [192][256] -> [256][192]
    int n = idx / 192, k = idx - n*192;
    wtin[idx] = f2bf(ipw[k*256 + n]);
  } else {
    int j = idx - 49152;          // gat: 4 x [256][256] -> [256][256]^T
    if (j < 262144){
      int l = j >> 16, rem = j & 65535;
      int n = rem >> 8, k = rem & 255;
      wtl[j] = f2bf(gatw[l*65536 + k*256 + n]);
    }
  }
}

// ---------------- vmat[l][16][256]: rows 0..3 = W^T·a_src heads, 4..7 = W^T·a_dst heads ----------------
__global__ __launch_bounds__(256) void k_vmat(
    const float* __restrict__ gatw, const float* __restrict__ asrc,
    const float* __restrict__ adst, u16* __restrict__ vmat)
{
  int idx = blockIdx.x*256 + threadIdx.x;   // 4*16*256 = 16384
  if (idx >= 16384) return;
  int l = idx >> 12, rem = idx & 4095, v = rem >> 8, k = rem & 255;
  float s = 0.f;
  if (v < 8){
    const float* a = (v < 4) ? (asrc + l*256 + v*64) : (adst + l*256 + (v-4)*64);
    const float* w = gatw + (size_t)l*65536 + k*256 + (v & 3)*64;
    #pragma unroll 8
    for (int c=0;c<64;++c) s += w[c]*a[c];
  }
  vmat[idx] = f2bf(s);
}

// ---------------- B-stationary MFMA GEMM ----------------
// C[M][256](bf16) = A[M][K](bf16) @ Wt[256][K]^T (+bias).
// Each block: B (wave's 64 cols x K) hoisted into registers ONCE; NT 64-row A-tiles
// DMA'd to LDS up-front (one vmcnt drain); K-loops are pure ds_read+MFMA.
// Wave 0 also computes score tile S = A @ vmat^T (cols 0..3 s_src, 4..7 s_dst).
template<int K, int NT>
__global__ __launch_bounds__(256, 2) void k_gemm(
    const u16* __restrict__ A, const u16* __restrict__ Wt,
    const float* __restrict__ bias, const u16* __restrict__ vmat,
    float* __restrict__ ss, float* __restrict__ sd,
    u16* __restrict__ C, int M)
{
  constexpr int CPR = K/8;            // 16B chunks per row
  constexpr int KS  = K/32;           // MFMA K-steps
  constexpr int TSZ = 64*K;           // u16 per staged tile
  constexpr int LDSE = (NT*TSZ > 16384) ? NT*TSZ : 16384;
  __shared__ u16 As[LDSE];
  int tid = threadIdx.x;
  int wave = tid >> 6, lane = tid & 63, quad = lane >> 4, lm = lane & 15;
  int c0 = wave * 64;

  // ---- stage all NT A-tiles via dma16 (coalesced, XOR-swizzled chunks) ----
  #pragma unroll
  for (int t = 0; t < NT; ++t){
    int r0 = (blockIdx.x*NT + t) * 64;
    for (int m = wave; m < TSZ/512; m += 4){
      int s = m*64 + lane;
      int r = s / CPR, p = s - r*CPR;
      int j = p ^ (r & 7);
      dma16(A + (size_t)(r0 + r)*K + j*8, As + (size_t)t*TSZ + (size_t)m*64*8);
    }
  }

  // ---- hoist B into registers (scattered L2 reads, once per block) ----
  bf16x8 breg[KS][4];
  #pragma unroll
  for (int ks = 0; ks < KS; ++ks)
    #pragma unroll
    for (int j = 0; j < 4; ++j)
      breg[ks][j] = *(const bf16x8*)(Wt + (size_t)(c0 + j*16 + lm)*K + ks*32 + quad*8);

  __syncthreads();   // dma drain

  #pragma unroll
  for (int t = 0; t < NT; ++t){
    int r0 = (blockIdx.x*NT + t) * 64;
    const u16* lbase = As + (size_t)t*TSZ;
    f32x4 acc[4][4] = {};
    f32x4 accs[4] = {};
    #pragma unroll
    for (int ks = 0; ks < KS; ++ks){
      bf16x8 a[4];
      #pragma unroll
      for (int i=0;i<4;++i){
        int slot = (i*16 + lm)*CPR + ((ks*4 + quad) ^ (lm & 7));
        a[i] = *(const bf16x8*)(lbase + (size_t)slot*8);
      }
      #pragma unroll
      for (int i=0;i<4;++i)
        #pragma unroll
        for (int j=0;j<4;++j)
          acc[i][j] = __builtin_amdgcn_mfma_f32_16x16x32_bf16(a[i], breg[ks][j], acc[i][j], 0, 0, 0);
      if (vmat && wave == 0){
        bf16x8 bs = *(const bf16x8*)(vmat + (size_t)lm*K + ks*32 + quad*8);
        #pragma unroll
        for (int i=0;i<4;++i)
          accs[i] = __builtin_amdgcn_mfma_f32_16x16x32_bf16(a[i], bs, accs[i], 0, 0, 0);
      }
    }

    // scores: C/D layout col=lane&15, row=quad*4+reg
    if (vmat && wave == 0){
      #pragma unroll
      for (int i=0;i<4;++i){
        #pragma unroll
        for (int r=0;r<4;++r){
          int row = r0 + i*16 + quad*4 + r;
          if (row < M){
            if (lm < 4)      ss[row*4 + lm]     = accs[i][r];
            else if (lm < 8) sd[row*4 + lm - 4] = accs[i][r];
          }
        }
      }
    }

    __syncthreads();  // all waves done reading this tile's LDS (and prior store's reads)
    // C tile (chunk-rotated by row) into LDS region [0,16384), then coalesced store
    #pragma unroll
    for (int i=0;i<4;++i){
      #pragma unroll
      for (int r=0;r<4;++r){
        int lrow = i*16 + quad*4 + r;
        #pragma unroll
        for (int j=0;j<4;++j){
          int col = c0 + j*16 + lm;
          float v = acc[i][j][r];
          if (bias) v += bias[col];
          int rc = (col + ((lrow & 31)*8)) & 255;
          As[lrow*256 + rc] = f2bf(v);
        }
      }
    }
    __syncthreads();
    {
      int lrow = tid >> 2;               // 64 rows, 4 threads/row
      int grow = r0 + lrow;
      if (grow < M){
        #pragma unroll
        for (int q=0;q<8;++q){
          int chunk = (tid & 3)*8 + q;
          int rchunk = (chunk + (lrow & 31)) & 31;
          uint4 v = *(const uint4*)(As + lrow*256 + rchunk*8);
          *(uint4*)(C + (size_t)grow*256 + chunk*8) = v;
        }
      }
    }
    if (t + 1 < NT) __syncthreads();  // store LDS-reads done before next C overwrite
  }
}

// ---------------- fused GAT aggregate + bias + relu + layernorm ----------------
// 2 nodes per wave (32 lanes x 8 ch), quad-edge unroll: 4 independent gather chains.
// single pass (no segment-max: |e| <~ 3 by construction)
__global__ __launch_bounds__(256) void k_aggregate(
    const u16* __restrict__ h2, const float* __restrict__ ssrc, const float* __restrict__ sdst,
    const int* __restrict__ row_off, const int* __restrict__ deg, const int* __restrict__ csr_src,
    const float* __restrict__ bias, const float* __restrict__ g, const float* __restrict__ bb,
    u16* __restrict__ hout)
{
  int wv = (blockIdx.x*blockDim.x + threadIdx.x) >> 6;
  int lane = threadIdx.x & 63;
  int half = lane >> 5;
  int hl = lane & 31;
  int n = wv*2 + half;
  if (n >= NN) return;
  int c0 = hl*8;
  int head = hl >> 3;
  float sdh = sdst[n*4 + head];
  int ro = row_off[n];
  int dg = deg[n];
  float den0=0,den1=0,den2=0,den3=0;
  float a0[8]={}, a1[8]={}, a2[8]={}, a3[8]={};
  int j = 0;
  for (; j + 4 <= dg; j += 4){
    int s0 = csr_src[ro+j],   s1 = csr_src[ro+j+1];
    int s2 = csr_src[ro+j+2], s3 = csr_src[ro+j+3];
    uint4 u0 = *(const uint4*)(h2 + (size_t)s0*HIDD + c0);
    uint4 u1 = *(const uint4*)(h2 + (size_t)s1*HIDD + c0);
    uint4 u2 = *(const uint4*)(h2 + (size_t)s2*HIDD + c0);
    uint4 u3 = *(const uint4*)(h2 + (size_t)s3*HIDD + c0);
    float e0 = ssrc[s0*4+head] + sdh; e0 = (e0>0.f)?e0:0.2f*e0;
    float e1 = ssrc[s1*4+head] + sdh; e1 = (e1>0.f)?e1:0.2f*e1;
    float e2 = ssrc[s2*4+head] + sdh; e2 = (e2>0.f)?e2:0.2f*e2;
    float e3 = ssrc[s3*4+head] + sdh; e3 = (e3>0.f)?e3:0.2f*e3;
    float x0=__expf(e0), x1=__expf(e1), x2=__expf(e2), x3=__expf(e3);
    den0+=x0; den1+=x1; den2+=x2; den3+=x3;
    a0[0]+=x0*bflo(u0.x); a0[1]+=x0*bfhi(u0.x); a0[2]+=x0*bflo(u0.y); a0[3]+=x0*bfhi(u0.y);
    a0[4]+=x0*bflo(u0.z); a0[5]+=x0*bfhi(u0.z); a0[6]+=x0*bflo(u0.w); a0[7]+=x0*bfhi(u0.w);
    a1[0]+=x1*bflo(u1.x); a1[1]+=x1*bfhi(u1.x); a1[2]+=x1*bflo(u1.y); a1[3]+=x1*bfhi(u1.y);
    a1[4]+=x1*bflo(u1.z); a1[5]+=x1*bfhi(u1.z); a1[6]+=x1*bflo(u1.w); a1[7]+=x1*bfhi(u1.w);
    a2[0]+=x2*bflo(u2.x); a2[1]+=x2*bfhi(u2.x); a2[2]+=x2*bflo(u2.y); a2[3]+=x2*bfhi(u2.y);
    a2[4]+=x2*bflo(u2.z); a2[5]+=x2*bfhi(u2.z); a2[6]+=x2*bflo(u2.w); a2[7]+=x2*bfhi(u2.w);
    a3[0]+=x3*bflo(u3.x); a3[1]+=x3*bfhi(u3.x); a3[2]+=x3*bflo(u3.y); a3[3]+=x3*bfhi(u3.y);
    a3[4]+=x3*bflo(u3.z); a3[5]+=x3*bfhi(u3.z); a3[6]+=x3*bflo(u3.w); a3[7]+=x3*bfhi(u3.w);
  }
  for (; j < dg; ++j){
    int s0 = csr_src[ro+j];
    uint4 u0 = *(const uint4*)(h2 + (size_t)s0*HIDD + c0);
    float e0 = ssrc[s0*4+head] + sdh; e0 = (e0>0.f)?e0:0.2f*e0;
    float x0 = __expf(e0);
    den0 += x0;
    a0[0]+=x0*bflo(u0.x); a0[1]+=x0*bfhi(u0.x); a0[2]+=x0*bflo(u0.y); a0[3]+=x0*bfhi(u0.y);
    a0[4]+=x0*bflo(u0.z); a0[5]+=x0*bfhi(u0.z); a0[6]+=x0*bflo(u0.w); a0[7]+=x0*bfhi(u0.w);
  }
  float inv = 1.f / ((den0+den1) + (den2+den3));
  float y[8];
  #pragma unroll
  for (int k=0;k<8;++k) y[k] = (a0[k]+a1[k]) + (a2[k]+a3[k]);
  float4 bi0 = *(const float4*)(bias + c0);
  float4 bi1 = *(const float4*)(bias + c0 + 4);
  y[0]=fmaxf(y[0]*inv+bi0.x,0.f); y[1]=fmaxf(y[1]*inv+bi0.y,0.f);
  y[2]=fmaxf(y[2]*inv+bi0.z,0.f); y[3]=fmaxf(y[3]*inv+bi0.w,0.f);
  y[4]=fmaxf(y[4]*inv+bi1.x,0.f); y[5]=fmaxf(y[5]*inv+bi1.y,0.f);
  y[6]=fmaxf(y[6]*inv+bi1.z,0.f); y[7]=fmaxf(y[7]*inv+bi1.w,0.f);
  // layernorm over 256 channels within the 32-lane half (xor-closed, offsets 1..16)
  float sum = (y[0]+y[1])+(y[2]+y[3])+((y[4]+y[5])+(y[6]+y[7]));
  #pragma unroll
  for (int o=16;o>=1;o>>=1) sum += __shfl_xor(sum, o);
  float mu = sum * (1.f/256.f);
  float d[8], sq = 0.f;
  #pragma unroll
  for (int k=0;k<8;++k){ d[k] = y[k]-mu; sq += d[k]*d[k]; }
  #pragma unroll
  for (int o=16;o>=1;o>>=1) sq += __shfl_xor(sq, o);
  float rs = rsqrtf(sq*(1.f/256.f) + LN_EPSF);
  float4 g0 = *(const float4*)(g + c0);
  float4 g1 = *(const float4*)(g + c0 + 4);
  float4 q0 = *(const float4*)(bb + c0);
  float4 q1 = *(const float4*)(bb + c0 + 4);
  uint4 o4;
  o4.x = pack2(d[0]*rs*g0.x + q0.x, d[1]*rs*g0.y + q0.y);
  o4.y = pack2(d[2]*rs*g0.z + q0.z, d[3]*rs*g0.w + q0.w);
  o4.z = pack2(d[4]*rs*g1.x + q1.x, d[5]*rs*g1.y + q1.y);
  o4.w = pack2(d[6]*rs*g1.z + q1.z, d[7]*rs*g1.w + q1.w);
  *(uint4*)(hout + (size_t)n*HIDD + c0) = o4;
}

// ---------------- global mean pool: 1024 blocks, run-length atomics (batch sorted) ----------------
__global__ __launch_bounds__(256) void k_pool(
    const u16* __restrict__ h, const int* __restrict__ batch,
    float* __restrict__ pooled, float* __restrict__ cnt)
{
  const int chunk = 49;  // 1024*49 >= NN
  int t = threadIdx.x;
  int n0 = blockIdx.x*chunk;
  int n1 = min(n0 + chunk, NN);
  if (n0 >= n1) return;
  float acc = 0.f;
  int curb = batch[n0];
  int runStart = n0;
  for (int n=n0; n<n1; ++n){
    int b = batch[n];
    if (b != curb){
      atomicAdd(&pooled[curb*HIDD + t], acc);
      if (t == 0) atomicAdd(&cnt[curb], (float)(n - runStart));
      acc = 0.f; curb = b; runStart = n;
    }
    acc += bf2f(h[(size_t)n*HIDD + t]);
  }
  atomicAdd(&pooled[curb*HIDD + t], acc);
  if (t == 0) atomicAdd(&cnt[curb], (float)(n1 - runStart));
}

// ---------------- readout: gelu(pooled@W1+b1)@W2+b2 (fp32, tiny) ----------------
__global__ __launch_bounds__(256) void k_readout(
    const float* __restrict__ pooled, const float* __restrict__ cnt,
    const float* __restrict__ w1, const float* __restrict__ b1,
    const float* __restrict__ w2, const float* __restrict__ b2,
    float* __restrict__ out)
{
  __shared__ float p[256], mid[256];
  int b = blockIdx.x, t = threadIdx.x;
  float c = fmaxf(cnt[b], 1.f);
  p[t] = pooled[b*HIDD + t] / c;
  __syncthreads();
  float acc = b1[t];
  for (int k=0;k<256;++k) acc += p[k]*w1[k*256+t];
  mid[t] = 0.5f*acc*(1.f + erff(acc*0.70710678118654752f));
  __syncthreads();
  float acc2 = b2[t];
  for (int k=0;k<256;++k) acc2 += mid[k]*w2[k*256+t];
  out[b*HIDD + t] = acc2;
}

extern "C" void kernel_launch(void* const* d_in, const int* in_sizes, int n_in,
                              void* d_out, int out_size, void* d_ws, size_t ws_size,
                              hipStream_t stream)
{
  const float* x    = (const float*)d_in[0];
  const float* remb = (const float*)d_in[1];
  const float* ipw  = (const float*)d_in[2];
  const float* ipb  = (const float*)d_in[3];
  const float* gatw = (const float*)d_in[4];
  const float* asrc = (const float*)d_in[5];
  const float* adst = (const float*)d_in[6];
  const float* gatb = (const float*)d_in[7];
  const float* lng  = (const float*)d_in[8];
  const float* lnb  = (const float*)d_in[9];
  const float* row1 = (const float*)d_in[10];
  const float* rob1 = (const float*)d_in[11];
  const float* row2 = (const float*)d_in[12];
  const float* rob2 = (const float*)d_in[13];
  const int* ei   = (const int*)d_in[14];
  const int* batch= (const int*)d_in[15];
  const int* rid  = (const int*)d_in[16];

  char* ws = (char*)d_ws;
  int*   deg  = (int*)  (ws + 0);          // 200192
  int*   cur  = (int*)  (ws + 200192);     // 200192
  float* cnt  = (float*)(ws + 400384);     // 256
  float* pool = (float*)(ws + 400640);     // 16384
  // ZERO_BYTES = 417024
  int*   row  = (int*)  (ws + 417024);     // 200192
  int*   part = (int*)  (ws + 617216);     // 1024
  int*   csr  = (int*)  (ws + 618240);     // 1800192 -> 2418432
  float* ss   = (float*)(ws + 2418432);    // 800768
  float* sd   = (float*)(ws + 3219200);    // 800768  -> 4019968
  u16*   vmat = (u16*)  (ws + 4019968);    // 32768   -> 4052736
  u16*   feats= (u16*)  (ws + 4052736);    // 19218432-> 23271168
  u16*   wtin = (u16*)  (ws + 23271168);   // 98304   -> 23369472
  u16*   wtl  = (u16*)  (ws + 23369472);   // 524288  -> 23893760
  u16*   hA   = (u16*)  (ws + 23893760);   // 25624576-> 49518336
  u16*   hB   = (u16*)  (ws + 49518336);   // 25624576-> 75142912

  hipMemsetAsync(ws, 0, 417024, stream);

  k_degree <<<1758, 256, 0, stream>>>(ei, deg);
  k_scan1  <<<196, 256, 0, stream>>>(deg, row, part);
  k_scan2  <<<1, 256, 0, stream>>>(part, 196);
  k_scan3  <<<196, 256, 0, stream>>>(row, part);
  k_scatter<<<1758, 256, 0, stream>>>(ei, row, cur, csr);
  k_feats  <<<12512, 256, 0, stream>>>(x, remb, rid, feats);
  k_wt     <<<1216, 256, 0, stream>>>(ipw, gatw, wtin, wtl);
  k_vmat   <<<64, 256, 0, stream>>>(gatw, asrc, adst, vmat);

  // input projection (bias, no scores): feats -> hA (=T); K=192, 1 tile/block
  k_gemm<KIN,1><<<MP/64, 256, 0, stream>>>(feats, wtin, ipb, nullptr,
                                           nullptr, nullptr, hA, NN);

  for (int l = 0; l < 4; ++l){
    // layer GEMM: hA -> hB, MFMA-fused scores via vmat[l]; K=256, 2 tiles/block
    k_gemm<HIDD,2><<<MP/128, 256, 0, stream>>>(hA, wtl + (size_t)l*HIDD*HIDD, nullptr,
                                               vmat + (size_t)l*16*256, ss, sd, hB, NN);
    k_aggregate<<<6250, 256, 0, stream>>>(hB, ss, sd, row, deg, csr,
                                          gatb + l*HIDD, lng + l*HIDD, lnb + l*HIDD, hA);
  }

  k_pool   <<<1024, 256, 0, stream>>>(hA, batch, pool, cnt);
  k_readout<<<16, 256, 0, stream>>>(pool, cnt, row1, rob1, row2, rob2, (float*)d_out);
}

// Round 10
// 516.855 us; speedup vs baseline: 1.1337x; 1.1337x over previous
//
#include <hip/hip_runtime.h>
#include <cmath>

typedef unsigned short u16;
typedef unsigned int u32;
typedef short bf16x8 __attribute__((ext_vector_type(8)));
typedef float f32x4 __attribute__((ext_vector_type(4)));

#define NN 50000      // nodes
#define MP 50048      // padded to 64
#define EE 400000     // raw edges
#define ET 450000     // edges + self loops
#define HIDD 256
#define KIN 192       // 3*F
#define LN_EPSF 1e-5f

__device__ __forceinline__ float bf2f(u16 u){ return __uint_as_float(((u32)u)<<16); }
__device__ __forceinline__ u16 f2bf(float f){
  u32 x = __float_as_uint(f);
  u32 r = x + 0x7fffu + ((x>>16)&1u);   // RNE
  return (u16)(r>>16);
}
__device__ __forceinline__ float bflo(u32 v){ return __uint_as_float(v<<16); }
__device__ __forceinline__ float bfhi(u32 v){ return __uint_as_float(v & 0xffff0000u); }
__device__ __forceinline__ u32 pack2(float a, float b){ return (u32)f2bf(a) | ((u32)f2bf(b)<<16); }

__device__ __forceinline__ void dma16(const u16* g, u16* lds){
  __builtin_amdgcn_global_load_lds(
      (const __attribute__((address_space(1))) void*)g,
      (__attribute__((address_space(3))) void*)lds, 16, 0, 0);
}

// ---------------- CSR build ----------------
__global__ void k_degree(const int* __restrict__ ei, int* __restrict__ deg){
  int i = blockIdx.x*blockDim.x + threadIdx.x;
  if (i >= ET) return;
  int d = (i < EE) ? ei[EE + i] : (i - EE);
  atomicAdd(&deg[d], 1);
}

__global__ void k_scan1(const int* __restrict__ deg, int* __restrict__ row_off, int* __restrict__ part){
  __shared__ int s[256];
  int n = blockIdx.x*256 + threadIdx.x;
  int v = (n < NN) ? deg[n] : 0;
  s[threadIdx.x] = v;
  __syncthreads();
  for (int off=1; off<256; off<<=1){
    int t = (threadIdx.x >= off) ? s[threadIdx.x - off] : 0;
    __syncthreads();
    s[threadIdx.x] += t;
    __syncthreads();
  }
  if (n < NN) row_off[n] = s[threadIdx.x] - v;
  if (threadIdx.x == 255) part[blockIdx.x] = s[255];
}

__global__ void k_scan2(int* __restrict__ part, int nparts){
  __shared__ int s[256];
  int v = (threadIdx.x < nparts) ? part[threadIdx.x] : 0;
  s[threadIdx.x] = v;
  __syncthreads();
  for (int off=1; off<256; off<<=1){
    int t = (threadIdx.x >= off) ? s[threadIdx.x - off] : 0;
    __syncthreads();
    s[threadIdx.x] += t;
    __syncthreads();
  }
  if (threadIdx.x < nparts) part[threadIdx.x] = s[threadIdx.x] - v;
}

__global__ void k_scan3(int* __restrict__ row_off, const int* __restrict__ part){
  int n = blockIdx.x*256 + threadIdx.x;
  if (n < NN) row_off[n] += part[blockIdx.x];
}

__global__ void k_scatter(const int* __restrict__ ei, const int* __restrict__ row_off,
                          int* __restrict__ cur, int* __restrict__ csr_src){
  int i = blockIdx.x*blockDim.x + threadIdx.x;
  if (i >= ET) return;
  int s, d;
  if (i < EE){ s = ei[i]; d = ei[EE + i]; } else { s = i - EE; d = i - EE; }
  int pos = row_off[d] + atomicAdd(&cur[d], 1);
  csr_src[pos] = s;
}

// ---------------- feats = [x | remb[rid] | posenc] as bf16 [MP][192], pad rows zeroed ----------------
__global__ __launch_bounds__(256) void k_feats(
    const float* __restrict__ x, const float* __restrict__ remb,
    const int* __restrict__ rid, u16* __restrict__ feats)
{
  int e = blockIdx.x*768 + threadIdx.x;
  #pragma unroll
  for (int it=0; it<3; ++it, e+=256){
    int n = e / 192;
    int c = e - n*192;
    if (n >= MP) break;
    float v = 0.f;
    if (n < NN){
      if (c < 64){
        v = x[n*64 + c];
      } else if (c < 128){
        v = remb[rid[n]*64 + (c-64)];
      } else {
        int i = c - 128;
        float rate = exp2f(-(float)(2*(i>>1)) * (1.0f/64.0f) * 13.287712379549449f);
        float s, cc;
        sincosf((float)n * rate, &s, &cc);
        v = (i & 1) ? cc : s;
      }
    }
    feats[(size_t)n*192 + c] = f2bf(v);
  }
}

// ---------------- weight convert+transpose to bf16 Wt[N][K] ----------------
__global__ __launch_bounds__(256) void k_wt(
    const float* __restrict__ ipw, const float* __restrict__ gatw,
    u16* __restrict__ wtin, u16* __restrict__ wtl)
{
  int idx = blockIdx.x*256 + threadIdx.x;
  if (idx < 49152){               // inproj: [192][256] -> [256][192]
    int n = idx / 192, k = idx - n*192;
    wtin[idx] = f2bf(ipw[k*256 + n]);
  } else {
    int j = idx - 49152;          // gat: 4 x [256][256] -> [256][256]^T
    if (j < 262144){
      int l = j >> 16, rem = j & 65535;
      int n = rem >> 8, k = rem & 255;
      wtl[j] = f2bf(gatw[l*65536 + k*256 + n]);
    }
  }
}

// ---------------- vmat[l][16][256]: rows 0..3 = W^T·a_src heads, 4..7 = W^T·a_dst heads ----------------
__global__ __launch_bounds__(256) void k_vmat(
    const float* __restrict__ gatw, const float* __restrict__ asrc,
    const float* __restrict__ adst, u16* __restrict__ vmat)
{
  int idx = blockIdx.x*256 + threadIdx.x;   // 4*16*256 = 16384
  if (idx >= 16384) return;
  int l = idx >> 12, rem = idx & 4095, v = rem >> 8, k = rem & 255;
  float s = 0.f;
  if (v < 8){
    const float* a = (v < 4) ? (asrc + l*256 + v*64) : (adst + l*256 + (v-4)*64);
    const float* w = gatw + (size_t)l*65536 + k*256 + (v & 3)*64;
    #pragma unroll 8
    for (int c=0;c<64;++c) s += w[c]*a[c];
  }
  vmat[idx] = f2bf(s);
}

// ---------------- phase-staged MFMA GEMM: both A and B tiles in LDS ----------------
// C[M][256](bf16) = A[M][K](bf16) @ Wt[256][K]^T (+bias).  K = NPH * 64 phases.
// Per phase: B (256x64, 32KB) + A (64x64, 8KB) DMA'd coalesced into LDS with XOR-
// swizzled chunks (CPR=8); K-loop is pure ds_read_b128 + MFMA (no global loads).
// Wave 0 also computes score tile S = A @ vmat^T (cols 0..3 s_src, 4..7 s_dst).
template<int K>
__global__ __launch_bounds__(256, 3) void k_gemm(
    const u16* __restrict__ A, const u16* __restrict__ Wt,
    const float* __restrict__ bias, const u16* __restrict__ vmat,
    float* __restrict__ ss, float* __restrict__ sd,
    u16* __restrict__ C, int M)
{
  constexpr int NPH = K/64;
  __shared__ u16 Bs[256*64];     // 32 KB (reused by C-tile epilogue)
  __shared__ u16 Asl[64*64];     // 8 KB
  int tid = threadIdx.x;
  int wave = tid >> 6, lane = tid & 63, quad = lane >> 4, lm = lane & 15;
  int r0 = blockIdx.x * 64, c0 = wave * 64;

  f32x4 acc[4][4] = {};
  f32x4 accs[4] = {};

  for (int ph = 0; ph < NPH; ++ph){
    // stage B phase tile: slot s = r*8 + (c ^ (r&7)), r = output col, c = chunk
    for (int m = wave; m < 32; m += 4){
      int s = m*64 + lane;
      int r = s >> 3, sc = s & 7;
      int c = sc ^ (r & 7);
      dma16(Wt + (size_t)r*K + ph*64 + c*8, Bs + (size_t)m*64*8);
    }
    // stage A phase tile
    for (int m = wave; m < 8; m += 4){
      int s = m*64 + lane;
      int r = s >> 3, sc = s & 7;
      int c = sc ^ (r & 7);
      dma16(A + (size_t)(r0 + r)*K + ph*64 + c*8, Asl + (size_t)m*64*8);
    }
    __syncthreads();   // vmcnt drain + barrier

    #pragma unroll
    for (int ks = 0; ks < 2; ++ks){
      bf16x8 a[4], b[4];
      #pragma unroll
      for (int j=0;j<4;++j){
        int row = c0 + j*16 + lm;
        b[j] = *(const bf16x8*)(Bs + (size_t)(row*8 + ((ks*4 + quad) ^ (row & 7)))*8);
      }
      #pragma unroll
      for (int i=0;i<4;++i){
        int row = i*16 + lm;
        a[i] = *(const bf16x8*)(Asl + (size_t)(row*8 + ((ks*4 + quad) ^ (row & 7)))*8);
      }
      #pragma unroll
      for (int i=0;i<4;++i)
        #pragma unroll
        for (int j=0;j<4;++j)
          acc[i][j] = __builtin_amdgcn_mfma_f32_16x16x32_bf16(a[i], b[j], acc[i][j], 0, 0, 0);
      if (vmat && wave == 0){
        bf16x8 bs = *(const bf16x8*)(vmat + (size_t)lm*K + ph*64 + ks*32 + quad*8);
        #pragma unroll
        for (int i=0;i<4;++i)
          accs[i] = __builtin_amdgcn_mfma_f32_16x16x32_bf16(a[i], bs, accs[i], 0, 0, 0);
      }
    }
    __syncthreads();   // LDS reads done before restage / epilogue reuse
  }

  // scores: C/D layout col=lane&15, row=quad*4+reg
  if (vmat && wave == 0){
    #pragma unroll
    for (int i=0;i<4;++i){
      #pragma unroll
      for (int r=0;r<4;++r){
        int row = r0 + i*16 + quad*4 + r;
        if (row < M){
          if (lm < 4)      ss[row*4 + lm]     = accs[i][r];
          else if (lm < 8) sd[row*4 + lm - 4] = accs[i][r];
        }
      }
    }
  }

  // C tile (chunk-rotated by row) into Bs, then coalesced store
  #pragma unroll
  for (int i=0;i<4;++i){
    #pragma unroll
    for (int r=0;r<4;++r){
      int lrow = i*16 + quad*4 + r;
      #pragma unroll
      for (int j=0;j<4;++j){
        int col = c0 + j*16 + lm;
        float v = acc[i][j][r];
        if (bias) v += bias[col];
        int rc = (col + ((lrow & 31)*8)) & 255;
        Bs[lrow*256 + rc] = f2bf(v);
      }
    }
  }
  __syncthreads();
  {
    int lrow = tid >> 2;               // 64 rows, 4 threads/row
    int grow = r0 + lrow;
    if (grow < M){
      #pragma unroll
      for (int q=0;q<8;++q){
        int chunk = (tid & 3)*8 + q;
        int rchunk = (chunk + (lrow & 31)) & 31;
        uint4 v = *(const uint4*)(Bs + lrow*256 + rchunk*8);
        *(uint4*)(C + (size_t)grow*256 + chunk*8) = v;
      }
    }
  }
}

// ---------------- fused GAT aggregate + bias + relu + layernorm ----------------
// 2 nodes per wave (32 lanes x 8 ch), quad-edge unroll: 4 independent gather chains.
// single pass (no segment-max: |e| <~ 3 by construction)
__global__ __launch_bounds__(256) void k_aggregate(
    const u16* __restrict__ h2, const float* __restrict__ ssrc, const float* __restrict__ sdst,
    const int* __restrict__ row_off, const int* __restrict__ deg, const int* __restrict__ csr_src,
    const float* __restrict__ bias, const float* __restrict__ g, const float* __restrict__ bb,
    u16* __restrict__ hout)
{
  int wv = (blockIdx.x*blockDim.x + threadIdx.x) >> 6;
  int lane = threadIdx.x & 63;
  int half = lane >> 5;
  int hl = lane & 31;
  int n = wv*2 + half;
  if (n >= NN) return;
  int c0 = hl*8;
  int head = hl >> 3;
  float sdh = sdst[n*4 + head];
  int ro = row_off[n];
  int dg = deg[n];
  float den0=0,den1=0,den2=0,den3=0;
  float a0[8]={}, a1[8]={}, a2[8]={}, a3[8]={};
  int j = 0;
  for (; j + 4 <= dg; j += 4){
    int s0 = csr_src[ro+j],   s1 = csr_src[ro+j+1];
    int s2 = csr_src[ro+j+2], s3 = csr_src[ro+j+3];
    uint4 u0 = *(const uint4*)(h2 + (size_t)s0*HIDD + c0);
    uint4 u1 = *(const uint4*)(h2 + (size_t)s1*HIDD + c0);
    uint4 u2 = *(const uint4*)(h2 + (size_t)s2*HIDD + c0);
    uint4 u3 = *(const uint4*)(h2 + (size_t)s3*HIDD + c0);
    float e0 = ssrc[s0*4+head] + sdh; e0 = (e0>0.f)?e0:0.2f*e0;
    float e1 = ssrc[s1*4+head] + sdh; e1 = (e1>0.f)?e1:0.2f*e1;
    float e2 = ssrc[s2*4+head] + sdh; e2 = (e2>0.f)?e2:0.2f*e2;
    float e3 = ssrc[s3*4+head] + sdh; e3 = (e3>0.f)?e3:0.2f*e3;
    float x0=__expf(e0), x1=__expf(e1), x2=__expf(e2), x3=__expf(e3);
    den0+=x0; den1+=x1; den2+=x2; den3+=x3;
    a0[0]+=x0*bflo(u0.x); a0[1]+=x0*bfhi(u0.x); a0[2]+=x0*bflo(u0.y); a0[3]+=x0*bfhi(u0.y);
    a0[4]+=x0*bflo(u0.z); a0[5]+=x0*bfhi(u0.z); a0[6]+=x0*bflo(u0.w); a0[7]+=x0*bfhi(u0.w);
    a1[0]+=x1*bflo(u1.x); a1[1]+=x1*bfhi(u1.x); a1[2]+=x1*bflo(u1.y); a1[3]+=x1*bfhi(u1.y);
    a1[4]+=x1*bflo(u1.z); a1[5]+=x1*bfhi(u1.z); a1[6]+=x1*bflo(u1.w); a1[7]+=x1*bfhi(u1.w);
    a2[0]+=x2*bflo(u2.x); a2[1]+=x2*bfhi(u2.x); a2[2]+=x2*bflo(u2.y); a2[3]+=x2*bfhi(u2.y);
    a2[4]+=x2*bflo(u2.z); a2[5]+=x2*bfhi(u2.z); a2[6]+=x2*bflo(u2.w); a2[7]+=x2*bfhi(u2.w);
    a3[0]+=x3*bflo(u3.x); a3[1]+=x3*bfhi(u3.x); a3[2]+=x3*bflo(u3.y); a3[3]+=x3*bfhi(u3.y);
    a3[4]+=x3*bflo(u3.z); a3[5]+=x3*bfhi(u3.z); a3[6]+=x3*bflo(u3.w); a3[7]+=x3*bfhi(u3.w);
  }
  for (; j < dg; ++j){
    int s0 = csr_src[ro+j];
    uint4 u0 = *(const uint4*)(h2 + (size_t)s0*HIDD + c0);
    float e0 = ssrc[s0*4+head] + sdh; e0 = (e0>0.f)?e0:0.2f*e0;
    float x0 = __expf(e0);
    den0 += x0;
    a0[0]+=x0*bflo(u0.x); a0[1]+=x0*bfhi(u0.x); a0[2]+=x0*bflo(u0.y); a0[3]+=x0*bfhi(u0.y);
    a0[4]+=x0*bflo(u0.z); a0[5]+=x0*bfhi(u0.z); a0[6]+=x0*bflo(u0.w); a0[7]+=x0*bfhi(u0.w);
  }
  float inv = 1.f / ((den0+den1) + (den2+den3));
  float y[8];
  #pragma unroll
  for (int k=0;k<8;++k) y[k] = (a0[k]+a1[k]) + (a2[k]+a3[k]);
  float4 bi0 = *(const float4*)(bias + c0);
  float4 bi1 = *(const float4*)(bias + c0 + 4);
  y[0]=fmaxf(y[0]*inv+bi0.x,0.f); y[1]=fmaxf(y[1]*inv+bi0.y,0.f);
  y[2]=fmaxf(y[2]*inv+bi0.z,0.f); y[3]=fmaxf(y[3]*inv+bi0.w,0.f);
  y[4]=fmaxf(y[4]*inv+bi1.x,0.f); y[5]=fmaxf(y[5]*inv+bi1.y,0.f);
  y[6]=fmaxf(y[6]*inv+bi1.z,0.f); y[7]=fmaxf(y[7]*inv+bi1.w,0.f);
  // layernorm over 256 channels within the 32-lane half (xor-closed, offsets 1..16)
  float sum = (y[0]+y[1])+(y[2]+y[3])+((y[4]+y[5])+(y[6]+y[7]));
  #pragma unroll
  for (int o=16;o>=1;o>>=1) sum += __shfl_xor(sum, o);
  float mu = sum * (1.f/256.f);
  float d[8], sq = 0.f;
  #pragma unroll
  for (int k=0;k<8;++k){ d[k] = y[k]-mu; sq += d[k]*d[k]; }
  #pragma unroll
  for (int o=16;o>=1;o>>=1) sq += __shfl_xor(sq, o);
  float rs = rsqrtf(sq*(1.f/256.f) + LN_EPSF);
  float4 g0 = *(const float4*)(g + c0);
  float4 g1 = *(const float4*)(g + c0 + 4);
  float4 q0 = *(const float4*)(bb + c0);
  float4 q1 = *(const float4*)(bb + c0 + 4);
  uint4 o4;
  o4.x = pack2(d[0]*rs*g0.x + q0.x, d[1]*rs*g0.y + q0.y);
  o4.y = pack2(d[2]*rs*g0.z + q0.z, d[3]*rs*g0.w + q0.w);
  o4.z = pack2(d[4]*rs*g1.x + q1.x, d[5]*rs*g1.y + q1.y);
  o4.w = pack2(d[6]*rs*g1.z + q1.z, d[7]*rs*g1.w + q1.w);
  *(uint4*)(hout + (size_t)n*HIDD + c0) = o4;
}

// ---------------- global mean pool: 1024 blocks, run-length atomics (batch sorted) ----------------
__global__ __launch_bounds__(256) void k_pool(
    const u16* __restrict__ h, const int* __restrict__ batch,
    float* __restrict__ pooled, float* __restrict__ cnt)
{
  const int chunk = 49;  // 1024*49 >= NN
  int t = threadIdx.x;
  int n0 = blockIdx.x*chunk;
  int n1 = min(n0 + chunk, NN);
  if (n0 >= n1) return;
  float acc = 0.f;
  int curb = batch[n0];
  int runStart = n0;
  for (int n=n0; n<n1; ++n){
    int b = batch[n];
    if (b != curb){
      atomicAdd(&pooled[curb*HIDD + t], acc);
      if (t == 0) atomicAdd(&cnt[curb], (float)(n - runStart));
      acc = 0.f; curb = b; runStart = n;
    }
    acc += bf2f(h[(size_t)n*HIDD + t]);
  }
  atomicAdd(&pooled[curb*HIDD + t], acc);
  if (t == 0) atomicAdd(&cnt[curb], (float)(n1 - runStart));
}

// ---------------- readout: gelu(pooled@W1+b1)@W2+b2 (fp32, tiny) ----------------
__global__ __launch_bounds__(256) void k_readout(
    const float* __restrict__ pooled, const float* __restrict__ cnt,
    const float* __restrict__ w1, const float* __restrict__ b1,
    const float* __restrict__ w2, const float* __restrict__ b2,
    float* __restrict__ out)
{
  __shared__ float p[256], mid[256];
  int b = blockIdx.x, t = threadIdx.x;
  float c = fmaxf(cnt[b], 1.f);
  p[t] = pooled[b*HIDD + t] / c;
  __syncthreads();
  float acc = b1[t];
  for (int k=0;k<256;++k) acc += p[k]*w1[k*256+t];
  mid[t] = 0.5f*acc*(1.f + erff(acc*0.70710678118654752f));
  __syncthreads();
  float acc2 = b2[t];
  for (int k=0;k<256;++k) acc2 += mid[k]*w2[k*256+t];
  out[b*HIDD + t] = acc2;
}

extern "C" void kernel_launch(void* const* d_in, const int* in_sizes, int n_in,
                              void* d_out, int out_size, void* d_ws, size_t ws_size,
                              hipStream_t stream)
{
  const float* x    = (const float*)d_in[0];
  const float* remb = (const float*)d_in[1];
  const float* ipw  = (const float*)d_in[2];
  const float* ipb  = (const float*)d_in[3];
  const float* gatw = (const float*)d_in[4];
  const float* asrc = (const float*)d_in[5];
  const float* adst = (const float*)d_in[6];
  const float* gatb = (const float*)d_in[7];
  const float* lng  = (const float*)d_in[8];
  const float* lnb  = (const float*)d_in[9];
  const float* row1 = (const float*)d_in[10];
  const float* rob1 = (const float*)d_in[11];
  const float* row2 = (const float*)d_in[12];
  const float* rob2 = (const float*)d_in[13];
  const int* ei   = (const int*)d_in[14];
  const int* batch= (const int*)d_in[15];
  const int* rid  = (const int*)d_in[16];

  char* ws = (char*)d_ws;
  int*   deg  = (int*)  (ws + 0);          // 200192
  int*   cur  = (int*)  (ws + 200192);     // 200192
  float* cnt  = (float*)(ws + 400384);     // 256
  float* pool = (float*)(ws + 400640);     // 16384
  // ZERO_BYTES = 417024
  int*   row  = (int*)  (ws + 417024);     // 200192
  int*   part = (int*)  (ws + 617216);     // 1024
  int*   csr  = (int*)  (ws + 618240);     // 1800192 -> 2418432
  float* ss   = (float*)(ws + 2418432);    // 800768
  float* sd   = (float*)(ws + 3219200);    // 800768  -> 4019968
  u16*   vmat = (u16*)  (ws + 4019968);    // 32768   -> 4052736
  u16*   feats= (u16*)  (ws + 4052736);    // 19218432-> 23271168
  u16*   wtin = (u16*)  (ws + 23271168);   // 98304   -> 23369472
  u16*   wtl  = (u16*)  (ws + 23369472);   // 524288  -> 23893760
  u16*   hA   = (u16*)  (ws + 23893760);   // 25624576-> 49518336
  u16*   hB   = (u16*)  (ws + 49518336);   // 25624576-> 75142912

  hipMemsetAsync(ws, 0, 417024, stream);

  k_degree <<<1758, 256, 0, stream>>>(ei, deg);
  k_scan1  <<<196, 256, 0, stream>>>(deg, row, part);
  k_scan2  <<<1, 256, 0, stream>>>(part, 196);
  k_scan3  <<<196, 256, 0, stream>>>(row, part);
  k_scatter<<<1758, 256, 0, stream>>>(ei, row, cur, csr);
  k_feats  <<<12512, 256, 0, stream>>>(x, remb, rid, feats);
  k_wt     <<<1216, 256, 0, stream>>>(ipw, gatw, wtin, wtl);
  k_vmat   <<<64, 256, 0, stream>>>(gatw, asrc, adst, vmat);

  // input projection (bias, no scores): feats -> hA ; K=192 (3 phases)
  k_gemm<KIN><<<MP/64, 256, 0, stream>>>(feats, wtin, ipb, nullptr,
                                         nullptr, nullptr, hA, NN);

  for (int l = 0; l < 4; ++l){
    // layer GEMM: hA -> hB, MFMA-fused scores via vmat[l]; K=256 (4 phases)
    k_gemm<HIDD><<<MP/64, 256, 0, stream>>>(hA, wtl + (size_t)l*HIDD*HIDD, nullptr,
                                            vmat + (size_t)l*16*256, ss, sd, hB, NN);
    k_aggregate<<<6250, 256, 0, stream>>>(hB, ss, sd, row, deg, csr,
                                          gatb + l*HIDD, lng + l*HIDD, lnb + l*HIDD, hA);
  }

  k_pool   <<<1024, 256, 0, stream>>>(hA, batch, pool, cnt);
  k_readout<<<16, 256, 0, stream>>>(pool, cnt, row1, rob1, row2, rob2, (float*)d_out);
}

// Round 11
// 493.283 us; speedup vs baseline: 1.1879x; 1.0478x over previous
//
#include <hip/hip_runtime.h>
#include <cmath>

typedef unsigned short u16;
typedef unsigned int u32;
typedef short bf16x8 __attribute__((ext_vector_type(8)));
typedef float f32x4 __attribute__((ext_vector_type(4)));

#define NN 50000      // nodes
#define MP 50048      // padded to 128*391
#define EE 400000     // raw edges
#define ET 450000     // edges + self loops
#define HIDD 256
#define KIN 192       // 3*F
#define LN_EPSF 1e-5f

__device__ __forceinline__ float bf2f(u16 u){ return __uint_as_float(((u32)u)<<16); }
__device__ __forceinline__ u16 f2bf(float f){
  u32 x = __float_as_uint(f);
  u32 r = x + 0x7fffu + ((x>>16)&1u);   // RNE
  return (u16)(r>>16);
}
__device__ __forceinline__ float bflo(u32 v){ return __uint_as_float(v<<16); }
__device__ __forceinline__ float bfhi(u32 v){ return __uint_as_float(v & 0xffff0000u); }
__device__ __forceinline__ u32 pack2(float a, float b){ return (u32)f2bf(a) | ((u32)f2bf(b)<<16); }

__device__ __forceinline__ void dma16(const u16* g, u16* lds){
  __builtin_amdgcn_global_load_lds(
      (const __attribute__((address_space(1))) void*)g,
      (__attribute__((address_space(3))) void*)lds, 16, 0, 0);
}

// ================ merged setup: feats | wt | vmat | degree (partitioned by block) ================
__global__ __launch_bounds__(256) void k_setup(
    const float* __restrict__ x, const float* __restrict__ remb, const int* __restrict__ rid,
    u16* __restrict__ feats,
    const float* __restrict__ ipw, const float* __restrict__ gatw,
    u16* __restrict__ wtin, u16* __restrict__ wtl,
    const float* __restrict__ asrc, const float* __restrict__ adst, u16* __restrict__ vmat,
    const int* __restrict__ ei, int* __restrict__ deg)
{
  int b = blockIdx.x;
  if (b < 12512){
    // ---- feats = [x | remb[rid] | posenc] bf16 [MP][192], pad rows zero ----
    int e = b*768 + threadIdx.x;
    #pragma unroll
    for (int it=0; it<3; ++it, e+=256){
      int n = e / 192;
      int c = e - n*192;
      if (n >= MP) break;
      float v = 0.f;
      if (n < NN){
        if (c < 64){
          v = x[n*64 + c];
        } else if (c < 128){
          v = remb[rid[n]*64 + (c-64)];
        } else {
          int i = c - 128;
          float rate = exp2f(-(float)(2*(i>>1)) * (1.0f/64.0f) * 13.287712379549449f);
          float s, cc;
          sincosf((float)n * rate, &s, &cc);
          v = (i & 1) ? cc : s;
        }
      }
      feats[(size_t)n*192 + c] = f2bf(v);
    }
  } else if (b < 13728){
    // ---- weight transpose to bf16 Wt[N][K] ----
    int idx = (b - 12512)*256 + threadIdx.x;
    if (idx < 49152){               // inproj: [192][256] -> [256][192]
      int n = idx / 192, k = idx - n*192;
      wtin[idx] = f2bf(ipw[k*256 + n]);
    } else {
      int j = idx - 49152;          // gat: 4 x [256][256]^T
      if (j < 262144){
        int l = j >> 16, rem = j & 65535;
        int n = rem >> 8, k = rem & 255;
        wtl[j] = f2bf(gatw[l*65536 + k*256 + n]);
      }
    }
  } else if (b < 13792){
    // ---- vmat[l][16][256]: rows 0..3 = W^T·a_src, 4..7 = W^T·a_dst, 8..15 zero ----
    int idx = (b - 13728)*256 + threadIdx.x;
    if (idx < 16384){
      int l = idx >> 12, rem = idx & 4095, v = rem >> 8, k = rem & 255;
      float s = 0.f;
      if (v < 8){
        const float* a = (v < 4) ? (asrc + l*256 + v*64) : (adst + l*256 + (v-4)*64);
        const float* w = gatw + (size_t)l*65536 + k*256 + (v & 3)*64;
        #pragma unroll 8
        for (int c=0;c<64;++c) s += w[c]*a[c];
      }
      vmat[idx] = f2bf(s);
    }
  } else {
    // ---- degree histogram ----
    int i = (b - 13792)*256 + threadIdx.x;
    if (i < ET){
      int d = (i < EE) ? ei[EE + i] : (i - EE);
      atomicAdd(&deg[d], 1);
    }
  }
}

// ---------------- scan1: per-block exclusive scan + block totals ----------------
__global__ void k_scan1(const int* __restrict__ deg, int* __restrict__ row_off, int* __restrict__ part){
  __shared__ int s[256];
  int n = blockIdx.x*256 + threadIdx.x;
  int v = (n < NN) ? deg[n] : 0;
  s[threadIdx.x] = v;
  __syncthreads();
  for (int off=1; off<256; off<<=1){
    int t = (threadIdx.x >= off) ? s[threadIdx.x - off] : 0;
    __syncthreads();
    s[threadIdx.x] += t;
    __syncthreads();
  }
  if (n < NN) row_off[n] = s[threadIdx.x] - v;
  if (threadIdx.x == 255) part[blockIdx.x] = s[255];
}

// ---------------- scan23: each block sums parts before it, adds to its row_offs ----------------
__global__ void k_scan23(int* __restrict__ row_off, const int* __restrict__ part, int nparts){
  __shared__ int sp[256];
  int t = threadIdx.x;
  sp[t] = (t < nparts && t < (int)blockIdx.x) ? part[t] : 0;
  __syncthreads();
  for (int off=128; off; off>>=1){
    if (t < off) sp[t] += sp[t+off];
    __syncthreads();
  }
  int n = blockIdx.x*256 + t;
  if (n < NN) row_off[n] += sp[0];
}

__global__ void k_scatter(const int* __restrict__ ei, const int* __restrict__ row_off,
                          int* __restrict__ cur, int* __restrict__ csr_src){
  int i = blockIdx.x*blockDim.x + threadIdx.x;
  if (i >= ET) return;
  int s, d;
  if (i < EE){ s = ei[i]; d = ei[EE + i]; } else { s = i - EE; d = i - EE; }
  int pos = row_off[d] + atomicAdd(&cur[d], 1);
  csr_src[pos] = s;
}

// ================ m97-style MFMA GEMM: 128x128 block tile, BK=32 ================
// C[M][256](bf16) = A[M][K](bf16) @ Wt[256][K]^T (+bias).  grid (391, 2).
// Per K-step: A-tile 128x32 (8KB) + B-tile 128x32 (8KB) staged via global_load_lds
// (XOR-swizzled 16B chunks), 2-barrier loop, pure ds_read_b128+MFMA inner.
// Waves: wave&1 = col half, wave>>1 = row half (64x64 quadrant each).
// Scores (S = A @ vmat^T) by waves 0,2 when cb==0.
template<int K>
__global__ __launch_bounds__(256, 3) void k_gemm(
    const u16* __restrict__ A, const u16* __restrict__ Wt,
    const float* __restrict__ bias, const u16* __restrict__ vmat,
    float* __restrict__ ss, float* __restrict__ sd,
    u16* __restrict__ C, int M)
{
  __shared__ u16 Asl[128*32];   // 8 KB  slot(r,p)=r*4+p holds chunk c=p^(r&3)
  __shared__ u16 Bsl[128*32];   // 8 KB
  int tid = threadIdx.x;
  int wave = tid >> 6, lane = tid & 63, quad = lane >> 4, lm = lane & 15;
  int r0 = blockIdx.x * 128;
  int cb = blockIdx.y;                   // col half of C (0/1)
  int rW = (wave >> 1) * 64;             // wave row offset in tile
  int cW = (wave & 1) * 64;              // wave col offset within the 128-col half
  bool doScore = vmat && (cb == 0) && ((wave & 1) == 0);

  f32x4 acc[4][4] = {};
  f32x4 accs[4] = {};

  for (int k0 = 0; k0 < K; k0 += 32){
    // stage A-tile: 512 chunks, 8 wave-instrs (2 per wave)
    for (int m = wave; m < 8; m += 4){
      int s = m*64 + lane;
      int r = s >> 2, p = s & 3;
      int c = p ^ (r & 3);
      dma16(A + (size_t)(r0 + r)*K + k0 + c*8, Asl + (size_t)m*512);
    }
    // stage B-tile (Wt rows cb*128 .. +127)
    for (int m = wave; m < 8; m += 4){
      int s = m*64 + lane;
      int r = s >> 2, p = s & 3;
      int c = p ^ (r & 3);
      dma16(Wt + (size_t)(cb*128 + r)*K + k0 + c*8, Bsl + (size_t)m*512);
    }
    __syncthreads();

    bf16x8 a[4], b[4];
    #pragma unroll
    for (int i=0;i<4;++i){
      int row = rW + i*16 + lm;
      a[i] = *(const bf16x8*)(Asl + (size_t)(row*4 + (quad ^ (row & 3)))*8);
    }
    #pragma unroll
    for (int j=0;j<4;++j){
      int row = cW + j*16 + lm;
      b[j] = *(const bf16x8*)(Bsl + (size_t)(row*4 + (quad ^ (row & 3)))*8);
    }
    #pragma unroll
    for (int i=0;i<4;++i)
      #pragma unroll
      for (int j=0;j<4;++j)
        acc[i][j] = __builtin_amdgcn_mfma_f32_16x16x32_bf16(a[i], b[j], acc[i][j], 0, 0, 0);
    if (doScore){
      bf16x8 bs = *(const bf16x8*)(vmat + (size_t)lm*K + k0 + quad*8);
      #pragma unroll
      for (int i=0;i<4;++i)
        accs[i] = __builtin_amdgcn_mfma_f32_16x16x32_bf16(a[i], bs, accs[i], 0, 0, 0);
    }
    __syncthreads();
  }

  // scores: C/D layout col=lane&15, row=quad*4+reg  [verified m89/m91]
  if (doScore){
    #pragma unroll
    for (int i=0;i<4;++i){
      #pragma unroll
      for (int r=0;r<4;++r){
        int row = r0 + rW + i*16 + quad*4 + r;
        if (row < M){
          if (lm < 4)      ss[row*4 + lm]     = accs[i][r];
          else if (lm < 8) sd[row*4 + lm - 4] = accs[i][r];
        }
      }
    }
  }

  // epilogue: direct stores (4x32B segments per inner store op)
  #pragma unroll
  for (int i=0;i<4;++i){
    #pragma unroll
    for (int r=0;r<4;++r){
      int row = r0 + rW + i*16 + quad*4 + r;
      if (row < M){
        #pragma unroll
        for (int j=0;j<4;++j){
          int col = cb*128 + cW + j*16 + lm;
          float v = acc[i][j][r];
          if (bias) v += bias[col];
          C[(size_t)row*256 + col] = f2bf(v);
        }
      }
    }
  }
}

// ---------------- fused GAT aggregate + bias + relu + layernorm ----------------
// 2 nodes per wave (32 lanes x 8 ch), dual-chain (R6 best: 43.2us, memory-floor)
__global__ __launch_bounds__(256) void k_aggregate(
    const u16* __restrict__ h2, const float* __restrict__ ssrc, const float* __restrict__ sdst,
    const int* __restrict__ row_off, const int* __restrict__ deg, const int* __restrict__ csr_src,
    const float* __restrict__ bias, const float* __restrict__ g, const float* __restrict__ bb,
    u16* __restrict__ hout)
{
  int wv = (blockIdx.x*blockDim.x + threadIdx.x) >> 6;
  int lane = threadIdx.x & 63;
  int half = lane >> 5;
  int hl = lane & 31;
  int n = wv*2 + half;
  if (n >= NN) return;
  int c0 = hl*8;
  int head = hl >> 3;
  float sdh = sdst[n*4 + head];
  int ro = row_off[n];
  int dg = deg[n];
  float denA = 0.f, denB = 0.f;
  float a0=0,a1=0,a2=0,a3=0,a4=0,a5=0,a6=0,a7=0;
  float b0=0,b1=0,b2=0,b3=0,b4=0,b5=0,b6=0,b7=0;
  int j = 0;
  for (; j + 2 <= dg; j += 2){
    int sA = csr_src[ro+j];
    int sB = csr_src[ro+j+1];
    uint4 uA = *(const uint4*)(h2 + (size_t)sA*HIDD + c0);
    uint4 uB = *(const uint4*)(h2 + (size_t)sB*HIDD + c0);
    float eA = ssrc[sA*4+head] + sdh;
    float eB = ssrc[sB*4+head] + sdh;
    eA = (eA > 0.f) ? eA : 0.2f*eA;
    eB = (eB > 0.f) ? eB : 0.2f*eB;
    float xA = __expf(eA), xB = __expf(eB);
    denA += xA; denB += xB;
    a0 += xA*bflo(uA.x); a1 += xA*bfhi(uA.x);
    a2 += xA*bflo(uA.y); a3 += xA*bfhi(uA.y);
    a4 += xA*bflo(uA.z); a5 += xA*bfhi(uA.z);
    a6 += xA*bflo(uA.w); a7 += xA*bfhi(uA.w);
    b0 += xB*bflo(uB.x); b1 += xB*bfhi(uB.x);
    b2 += xB*bflo(uB.y); b3 += xB*bfhi(uB.y);
    b4 += xB*bflo(uB.z); b5 += xB*bfhi(uB.z);
    b6 += xB*bflo(uB.w); b7 += xB*bfhi(uB.w);
  }
  if (j < dg){
    int sA = csr_src[ro+j];
    uint4 uA = *(const uint4*)(h2 + (size_t)sA*HIDD + c0);
    float eA = ssrc[sA*4+head] + sdh;
    eA = (eA > 0.f) ? eA : 0.2f*eA;
    float xA = __expf(eA);
    denA += xA;
    a0 += xA*bflo(uA.x); a1 += xA*bfhi(uA.x);
    a2 += xA*bflo(uA.y); a3 += xA*bfhi(uA.y);
    a4 += xA*bflo(uA.z); a5 += xA*bfhi(uA.z);
    a6 += xA*bflo(uA.w); a7 += xA*bfhi(uA.w);
  }
  float inv = 1.f / (denA + denB);
  float y[8];
  y[0]=a0+b0; y[1]=a1+b1; y[2]=a2+b2; y[3]=a3+b3;
  y[4]=a4+b4; y[5]=a5+b5; y[6]=a6+b6; y[7]=a7+b7;
  float4 bi0 = *(const float4*)(bias + c0);
  float4 bi1 = *(const float4*)(bias + c0 + 4);
  y[0]=fmaxf(y[0]*inv+bi0.x,0.f); y[1]=fmaxf(y[1]*inv+bi0.y,0.f);
  y[2]=fmaxf(y[2]*inv+bi0.z,0.f); y[3]=fmaxf(y[3]*inv+bi0.w,0.f);
  y[4]=fmaxf(y[4]*inv+bi1.x,0.f); y[5]=fmaxf(y[5]*inv+bi1.y,0.f);
  y[6]=fmaxf(y[6]*inv+bi1.z,0.f); y[7]=fmaxf(y[7]*inv+bi1.w,0.f);
  // layernorm over 256 channels within the 32-lane half (xor-closed, offsets 1..16)
  float sum = (y[0]+y[1])+(y[2]+y[3])+((y[4]+y[5])+(y[6]+y[7]));
  #pragma unroll
  for (int o=16;o>=1;o>>=1) sum += __shfl_xor(sum, o);
  float mu = sum * (1.f/256.f);
  float d[8], sq = 0.f;
  #pragma unroll
  for (int k=0;k<8;++k){ d[k] = y[k]-mu; sq += d[k]*d[k]; }
  #pragma unroll
  for (int o=16;o>=1;o>>=1) sq += __shfl_xor(sq, o);
  float rs = rsqrtf(sq*(1.f/256.f) + LN_EPSF);
  float4 g0 = *(const float4*)(g + c0);
  float4 g1 = *(const float4*)(g + c0 + 4);
  float4 q0 = *(const float4*)(bb + c0);
  float4 q1 = *(const float4*)(bb + c0 + 4);
  uint4 o4;
  o4.x = pack2(d[0]*rs*g0.x + q0.x, d[1]*rs*g0.y + q0.y);
  o4.y = pack2(d[2]*rs*g0.z + q0.z, d[3]*rs*g0.w + q0.w);
  o4.z = pack2(d[4]*rs*g1.x + q1.x, d[5]*rs*g1.y + q1.y);
  o4.w = pack2(d[6]*rs*g1.z + q1.z, d[7]*rs*g1.w + q1.w);
  *(uint4*)(hout + (size_t)n*HIDD + c0) = o4;
}

// ---------------- global mean pool: 2000 blocks, run-length atomics (batch sorted) ----------------
__global__ __launch_bounds__(256) void k_pool(
    const u16* __restrict__ h, const int* __restrict__ batch,
    float* __restrict__ pooled, float* __restrict__ cnt)
{
  const int chunk = 25;  // 2000*25 >= NN
  int t = threadIdx.x;
  int n0 = blockIdx.x*chunk;
  int n1 = min(n0 + chunk, NN);
  if (n0 >= n1) return;
  float acc = 0.f;
  int curb = batch[n0];
  int runStart = n0;
  for (int n=n0; n<n1; ++n){
    int b = batch[n];
    if (b != curb){
      atomicAdd(&pooled[curb*HIDD + t], acc);
      if (t == 0) atomicAdd(&cnt[curb], (float)(n - runStart));
      acc = 0.f; curb = b; runStart = n;
    }
    acc += bf2f(h[(size_t)n*HIDD + t]);
  }
  atomicAdd(&pooled[curb*HIDD + t], acc);
  if (t == 0) atomicAdd(&cnt[curb], (float)(n1 - runStart));
}

// ---------------- readout: gelu(pooled@W1+b1)@W2+b2 (fp32, tiny) ----------------
__global__ __launch_bounds__(256) void k_readout(
    const float* __restrict__ pooled, const float* __restrict__ cnt,
    const float* __restrict__ w1, const float* __restrict__ b1,
    const float* __restrict__ w2, const float* __restrict__ b2,
    float* __restrict__ out)
{
  __shared__ float p[256], mid[256];
  int b = blockIdx.x, t = threadIdx.x;
  float c = fmaxf(cnt[b], 1.f);
  p[t] = pooled[b*HIDD + t] / c;
  __syncthreads();
  float acc = b1[t];
  for (int k=0;k<256;++k) acc += p[k]*w1[k*256+t];
  mid[t] = 0.5f*acc*(1.f + erff(acc*0.70710678118654752f));
  __syncthreads();
  float acc2 = b2[t];
  for (int k=0;k<256;++k) acc2 += mid[k]*w2[k*256+t];
  out[b*HIDD + t] = acc2;
}

extern "C" void kernel_launch(void* const* d_in, const int* in_sizes, int n_in,
                              void* d_out, int out_size, void* d_ws, size_t ws_size,
                              hipStream_t stream)
{
  const float* x    = (const float*)d_in[0];
  const float* remb = (const float*)d_in[1];
  const float* ipw  = (const float*)d_in[2];
  const float* ipb  = (const float*)d_in[3];
  const float* gatw = (const float*)d_in[4];
  const float* asrc = (const float*)d_in[5];
  const float* adst = (const float*)d_in[6];
  const float* gatb = (const float*)d_in[7];
  const float* lng  = (const float*)d_in[8];
  const float* lnb  = (const float*)d_in[9];
  const float* row1 = (const float*)d_in[10];
  const float* rob1 = (const float*)d_in[11];
  const float* row2 = (const float*)d_in[12];
  const float* rob2 = (const float*)d_in[13];
  const int* ei   = (const int*)d_in[14];
  const int* batch= (const int*)d_in[15];
  const int* rid  = (const int*)d_in[16];

  char* ws = (char*)d_ws;
  int*   deg  = (int*)  (ws + 0);          // 200192
  int*   cur  = (int*)  (ws + 200192);     // 200192
  float* cnt  = (float*)(ws + 400384);     // 256
  float* pool = (float*)(ws + 400640);     // 16384
  // ZERO_BYTES = 417024
  int*   row  = (int*)  (ws + 417024);     // 200192
  int*   part = (int*)  (ws + 617216);     // 1024
  int*   csr  = (int*)  (ws + 618240);     // 1800192 -> 2418432
  float* ss   = (float*)(ws + 2418432);    // 800768
  float* sd   = (float*)(ws + 3219200);    // 800768  -> 4019968
  u16*   vmat = (u16*)  (ws + 4019968);    // 32768   -> 4052736
  u16*   feats= (u16*)  (ws + 4052736);    // 19218432-> 23271168
  u16*   wtin = (u16*)  (ws + 23271168);   // 98304   -> 23369472
  u16*   wtl  = (u16*)  (ws + 23369472);   // 524288  -> 23893760
  u16*   hA   = (u16*)  (ws + 23893760);   // 25624576-> 49518336
  u16*   hB   = (u16*)  (ws + 49518336);   // 25624576-> 75142912

  hipMemsetAsync(ws, 0, 417024, stream);

  k_setup <<<15550, 256, 0, stream>>>(x, remb, rid, feats, ipw, gatw, wtin, wtl,
                                      asrc, adst, vmat, ei, deg);
  k_scan1 <<<196, 256, 0, stream>>>(deg, row, part);
  k_scan23<<<196, 256, 0, stream>>>(row, part, 196);
  k_scatter<<<1758, 256, 0, stream>>>(ei, row, cur, csr);

  // input projection (bias, no scores): feats -> hA ; K=192
  k_gemm<KIN><<<dim3(391,2), 256, 0, stream>>>(feats, wtin, ipb, nullptr,
                                               nullptr, nullptr, hA, NN);

  for (int l = 0; l < 4; ++l){
    // layer GEMM: hA -> hB, MFMA-fused scores via vmat[l]; K=256
    k_gemm<HIDD><<<dim3(391,2), 256, 0, stream>>>(hA, wtl + (size_t)l*HIDD*HIDD, nullptr,
                                                  vmat + (size_t)l*16*256, ss, sd, hB, NN);
    k_aggregate<<<6250, 256, 0, stream>>>(hB, ss, sd, row, deg, csr,
                                          gatb + l*HIDD, lng + l*HIDD, lnb + l*HIDD, hA);
  }

  k_pool   <<<2000, 256, 0, stream>>>(hA, batch, pool, cnt);
  k_readout<<<16, 256, 0, stream>>>(pool, cnt, row1, rob1, row2, rob2, (float*)d_out);
}